// Round 5
// baseline (26.980 us; speedup 1.0000x reference)
//
#include <hip/hip_runtime.h>

// DiffusionInitializer: out = P*noise + (1-P)*(latent @ W + b), P = prod(t/steps)
// Closed form of the 50-step scan (convex combos; weights sum to 1;
// P = steps!/steps^steps ~ 3.5e-21).
//
// R4 post-mortem: 26.3 us = 5.15 TB/s effective vs ~6.3 TB/s read ceiling.
// R5: (a) prefetch depth 2 (8 KB in flight per wave, 128 KB/CU);
//     (b) noise load + out store coalesced across lanes 0-2 (one 12B
//         wave-transaction each instead of 3+3 lane-0 scalars; per-row VMEM
//         instruction count 10 -> 6);
//     (c) persistent 1024 blocks, nt latent loads (unchanged).

#define D_DIM 1024
#define NCHUNK (D_DIM / 256)   // 4 vec4-chunks of 64 lanes each per row

typedef float floatx4 __attribute__((ext_vector_type(4)));

__launch_bounds__(256, 4)
__global__ void diffusion_init_kernel(const float* __restrict__ latent,
                                      const float* __restrict__ W,
                                      const float* __restrict__ bias,
                                      const float* __restrict__ noise,
                                      const int* __restrict__ steps_p,
                                      float* __restrict__ out,
                                      int rows) {
    const int lane   = threadIdx.x & 63;
    const int wid    = (blockIdx.x * blockDim.x + threadIdx.x) >> 6;
    const int nwaves = (gridDim.x * blockDim.x) >> 6;

    // Per-lane W fragment: chunk j covers d = j*256 + lane*4 + k, cols 0..2.
    // W rows d..d+3 = 12 consecutive floats at vec4-offset j*192 + lane*3.
    float wv[NCHUNK][12];
    const floatx4* W4 = (const floatx4*)W;
    #pragma unroll
    for (int j = 0; j < NCHUNK; ++j) {
        #pragma unroll
        for (int q = 0; q < 3; ++q) {
            floatx4 t = W4[j * 192 + lane * 3 + q];
            wv[j][q * 4 + 0] = t.x;
            wv[j][q * 4 + 1] = t.y;
            wv[j][q * 4 + 2] = t.z;
            wv[j][q * 4 + 3] = t.w;
        }
    }
    // per-lane bias element for the coalesced store (lanes 0..2 store cols 0..2)
    const float bl = bias[lane < 3 ? lane : 0];

    // P in log2-space (P ~ 3.5e-21 at steps=50): cheap transcendentals.
    int steps = steps_p[0];
    if (steps <= 0 || steps > (1 << 20)) {
        float fs = __int_as_float(steps);
        steps = (fs >= 1.0f && fs < 1.0e6f) ? (int)(fs + 0.5f) : 50;
    }
    const int nt = steps < 2048 ? steps : 2048;
    float logp = 0.f;
    const float ls = __log2f((float)steps);
    for (int t = 1; t <= nt; ++t) logp += __log2f((float)t) - ls;
    const float P   = exp2f(logp);
    const float omP = 1.0f - P;

    const floatx4* L4 = (const floatx4*)latent;

    // ---- depth-2 register pipeline ----
    floatx4 cur[NCHUNK], nx1[NCHUNK];
    {
        const int r0 = wid, r1 = wid + nwaves;
        if (r0 < rows) {
            const size_t rb = (size_t)r0 * (D_DIM / 4);
            #pragma unroll
            for (int j = 0; j < NCHUNK; ++j)
                cur[j] = __builtin_nontemporal_load(&L4[rb + j * 64 + lane]);
        }
        if (r1 < rows) {
            const size_t rb = (size_t)r1 * (D_DIM / 4);
            #pragma unroll
            for (int j = 0; j < NCHUNK; ++j)
                nx1[j] = __builtin_nontemporal_load(&L4[rb + j * 64 + lane]);
        }
    }

    for (int row = wid; row < rows; row += nwaves) {
        // ---- prefetch row+2*nwaves (stays in flight across 2 iterations) ----
        floatx4 nx2[NCHUNK];
        const int prow = row + 2 * nwaves;
        if (prow < rows) {
            const size_t pb = (size_t)prow * (D_DIM / 4);
            #pragma unroll
            for (int j = 0; j < NCHUNK; ++j)
                nx2[j] = __builtin_nontemporal_load(&L4[pb + j * 64 + lane]);
        }

        // ---- coalesced noise pre-load: lanes 0..2 read 12 contiguous bytes ----
        const size_t o = (size_t)row * 3;
        float nv = 0.f;
        if (lane < 3) nv = noise[o + lane];

        // ---- 3 FMA chains over this row's 16 d-values ----
        float a0 = 0.f, a1 = 0.f, a2 = 0.f;
        #pragma unroll
        for (int j = 0; j < NCHUNK; ++j) {
            const floatx4 t = cur[j];
            a0 = fmaf(t.x, wv[j][0], a0);
            a1 = fmaf(t.x, wv[j][1], a1);
            a2 = fmaf(t.x, wv[j][2], a2);
            a0 = fmaf(t.y, wv[j][3], a0);
            a1 = fmaf(t.y, wv[j][4], a1);
            a2 = fmaf(t.y, wv[j][5], a2);
            a0 = fmaf(t.z, wv[j][6], a0);
            a1 = fmaf(t.z, wv[j][7], a1);
            a2 = fmaf(t.z, wv[j][8], a2);
            a0 = fmaf(t.w, wv[j][9], a0);
            a1 = fmaf(t.w, wv[j][10], a1);
            a2 = fmaf(t.w, wv[j][11], a2);
        }

        // ---- 64-lane butterfly allreduce (3 independent 6-deep chains) ----
        #pragma unroll
        for (int off = 32; off > 0; off >>= 1) {
            a0 += __shfl_xor(a0, off, 64);
            a1 += __shfl_xor(a1, off, 64);
            a2 += __shfl_xor(a2, off, 64);
        }

        // ---- coalesced store: lanes 0..2 write 12 contiguous bytes ----
        if (lane < 3) {
            const float sl = lane == 0 ? a0 : lane == 1 ? a1 : a2;
            out[o + lane] = omP * (sl + bl) + P * nv;
        }

        // ---- rotate pipeline registers ----
        #pragma unroll
        for (int j = 0; j < NCHUNK; ++j) { cur[j] = nx1[j]; nx1[j] = nx2[j]; }
    }
}

extern "C" void kernel_launch(void* const* d_in, const int* in_sizes, int n_in,
                              void* d_out, int out_size, void* d_ws, size_t ws_size,
                              hipStream_t stream) {
    const float* latent = (const float*)d_in[0];
    const float* W      = (const float*)d_in[1];
    const float* bias   = (const float*)d_in[2];
    const float* noise  = (const float*)d_in[3];
    const int*   steps  = (const int*)d_in[4];
    float* out = (float*)d_out;

    const int rows = in_sizes[3] / 3;  // B*S = 32768

    // 1024 blocks = 4 blocks/CU = 16 waves/CU (4 waves/SIMD residency);
    // 4096 waves -> 8 pipelined grid-stride iterations per wave.
    const int blocks = 1024;
    diffusion_init_kernel<<<blocks, 256, 0, stream>>>(latent, W, bias, noise,
                                                      steps, out, rows);
}